// Round 18
// baseline (1237.889 us; speedup 1.0000x reference)
//
#include <hip/hip_runtime.h>
#include <hip/hip_bf16.h>

typedef __bf16    bf16x8_t __attribute__((ext_vector_type(8)));
typedef float     f32x4_t  __attribute__((ext_vector_type(4)));
typedef short     s16x4_t  __attribute__((ext_vector_type(4)));
typedef short     s16x8_t  __attribute__((ext_vector_type(8)));
typedef unsigned  u32x4_t  __attribute__((ext_vector_type(4)));

#define S_LEN 2048
#define HDIM  64
#define BQ    32
#define NTHREADS 1024
#define PSTR_B 4112
#define BMSTR 264

__device__ __forceinline__ short f2bf(float f) {
    return __builtin_bit_cast(short, (__bf16)f);
}
__device__ __forceinline__ float bf2f(short s) {
    return __builtin_bit_cast(float, ((unsigned)(unsigned short)s) << 16);
}
__device__ __forceinline__ short* pelem(short* P, int row, int e) {
    return (short*)((char*)P + (unsigned)row * PSTR_B + (unsigned)e * 2u);
}
__device__ __forceinline__ const short* pelemc(const short* P, int row, int e) {
    return pelem(const_cast<short*>(P), row, e);
}
__device__ __forceinline__ unsigned nzmask16(u32x4_t w) {
    unsigned n = 0;
    #pragma unroll
    for (int i = 0; i < 4; ++i) {
        const unsigned x = w[i];
        const unsigned t = (x & 0x7F7F7F7Fu) + 0x7F7F7F7Fu;
        const unsigned z = ((t | x) & 0x80808080u) >> 7;
        n |= ((z * 0x10204081u) >> 28) << (4 * i);
    }
    return n;
}
__device__ __forceinline__ unsigned nzmask4w(u32x4_t w) {
    return (w[0] ? 1u : 0u) | (w[1] ? 2u : 0u) | (w[2] ? 4u : 0u) | (w[3] ? 8u : 0u);
}

#define PK8(lo, hi, out8) { s16x8_t _t; \
    _t[0]=f2bf((lo)[0]); _t[1]=f2bf((lo)[1]); _t[2]=f2bf((lo)[2]); _t[3]=f2bf((lo)[3]); \
    _t[4]=f2bf((hi)[0]); _t[5]=f2bf((hi)[1]); _t[6]=f2bf((hi)[2]); _t[7]=f2bf((hi)[3]); \
    (out8) = __builtin_bit_cast(bf16x8_t, _t); }
#define PKV(src, dst) { s16x8_t _t; \
    _t[0]=f2bf((src)[0]); _t[1]=f2bf((src)[1]); _t[2]=f2bf((src)[2]); _t[3]=f2bf((src)[3]); \
    _t[4]=f2bf((src)[4]); _t[5]=f2bf((src)[5]); _t[6]=f2bf((src)[6]); _t[7]=f2bf((src)[7]); \
    (dst) = __builtin_bit_cast(bf16x8_t, _t); }

__global__ void detect_mask(const unsigned char* __restrict__ M, int* __restrict__ flags) {
    __shared__ int cnt[4];
    if (threadIdx.x < 4) cnt[threadIdx.x] = 0;
    __syncthreads();
    int local[4] = {0, 0, 0, 0};
    for (int i = threadIdx.x; i < 16384; i += 256)
        if (M[i]) local[i & 3]++;
    #pragma unroll
    for (int c = 0; c < 4; ++c)
        if (local[c]) atomicAdd(&cnt[c], local[c]);
    __syncthreads();
    if (threadIdx.x == 0) {
        int stride;
        if (cnt[1] == 0 && cnt[2] == 0 && cnt[3] == 0)      stride = 4;  // int32
        else if (cnt[0] == 0 && cnt[1] == 0)                stride = 4;  // float32
        else                                                stride = 1;  // bool/int8
        flags[0] = stride;
    }
}

// PROBE K (grid 4096 = 2x): K loads + PK8 + MFMA only; epilogue replaced by
// 8 adds into rs (keeps MFMA live). Same LDS footprint (1 block/CU).
__global__ __launch_bounds__(NTHREADS, 1)
void probe_k(const float* __restrict__ Q, const float* __restrict__ K,
             float* __restrict__ OUT)
{
    __shared__ short Plds[BQ * (PSTR_B / 2)];
    __shared__ float rowsum[BQ];

    const int tid  = threadIdx.x;
    const int w    = tid >> 6;
    const int lane = tid & 63;
    const int col  = lane & 15;
    const int kg   = lane >> 4;

    const int id2  = blockIdx.x & 2047;
    const int slot = id2 >> 3;
    const int b    = ((slot >> 6) << 3) | (id2 & 7);
    const int q0   = (slot & 63) * BQ;

    if (tid < BQ) rowsum[tid] = 0.f;

    bf16x8_t af[2][2];
    #pragma unroll
    for (int m = 0; m < 2; ++m)
        #pragma unroll
        for (int kk = 0; kk < 2; ++kk) {
            const float* qp = Q + ((size_t)b * S_LEN + q0 + m * 16 + col) * HDIM + kk * 32 + kg * 8;
            const f32x4_t qa = *(const f32x4_t*)qp;
            const f32x4_t qb = *(const f32x4_t*)(qp + 4);
            PK8(qa, qb, af[m][kk]);
        }
    __syncthreads();

    float rs0 = 0.f, rs1 = 0.f;
    {
        const float* Kb = K + (size_t)b * S_LEN * HDIM;
        f32x4_t A0,B0,C0,D0, A1,B1,C1,D1;
#define LDK(f, AX,BX,CX,DX) { \
    const float* kp = Kb + (size_t)(w * 128 + (f) * 16 + col) * HDIM + kg * 8; \
    AX = *(const f32x4_t*)kp;        BX = *(const f32x4_t*)(kp + 4); \
    CX = *(const f32x4_t*)(kp + 32); DX = *(const f32x4_t*)(kp + 36); }
#define STEPK(f, AX,BX,CX,DX, PF, fp) { \
    bf16x8_t kb0, kb1; PK8(AX, BX, kb0); PK8(CX, DX, kb1); \
    if (PF) LDK(fp, AX,BX,CX,DX); \
    f32x4_t acc0 = {0.f,0.f,0.f,0.f}, acc1 = {0.f,0.f,0.f,0.f}; \
    acc0 = __builtin_amdgcn_mfma_f32_16x16x32_bf16(kb0, af[0][0], acc0, 0,0,0); \
    acc0 = __builtin_amdgcn_mfma_f32_16x16x32_bf16(kb1, af[0][1], acc0, 0,0,0); \
    acc1 = __builtin_amdgcn_mfma_f32_16x16x32_bf16(kb0, af[1][0], acc1, 0,0,0); \
    acc1 = __builtin_amdgcn_mfma_f32_16x16x32_bf16(kb1, af[1][1], acc1, 0,0,0); \
    rs0 += (acc0[0] + acc0[1]) + (acc0[2] + acc0[3]); \
    rs1 += (acc1[0] + acc1[1]) + (acc1[2] + acc1[3]); }
        LDK(0, A0,B0,C0,D0);
        LDK(1, A1,B1,C1,D1);
        #pragma unroll
        for (int ff = 0; ff < 8; ff += 2) {
            STEPK(ff,     A0,B0,C0,D0, (ff + 2 < 8), ff + 2);
            STEPK(ff + 1, A1,B1,C1,D1, (ff + 3 < 8), ff + 3);
        }
#undef LDK
#undef STEPK
    }
    // keep rs + Plds live; garbage into ctx region (overwritten by main)
    Plds[tid] = f2bf(rs0);
    Plds[1024 + tid] = f2bf(rs1);
    __syncthreads();
    const float g = bf2f(Plds[(tid * 7) & 2047]);
    if (lane == 0)
        OUT[((size_t)b * S_LEN + q0 + (w & 31)) * HDIM] = g * 1e-30f;
}

// PROBE SER (grid 4096 = 2x): FULL r17 phase 1 (mask bitmask + epilogue +
// ds_writes + rowsum) but K addresses clamped to rows 0..127 -> data always
// L1/L2-hot; instruction stream otherwise identical. Latency-free variant.
__global__ __launch_bounds__(NTHREADS, 1)
void probe_ser(const float* __restrict__ Q, const float* __restrict__ K,
               const unsigned char* __restrict__ M, const int* __restrict__ MF,
               float* __restrict__ OUT)
{
    __shared__ short Plds[BQ * (PSTR_B / 2)];
    __shared__ unsigned char Bm[BQ * BMSTR];
    __shared__ float rowsum[BQ];
    __shared__ float rinv_s[BQ];

    const int tid  = threadIdx.x;
    const int w    = tid >> 6;
    const int lane = tid & 63;
    const int col  = lane & 15;
    const int kg   = lane >> 4;
    const int mstride = MF[0];

    const int id2  = blockIdx.x & 2047;
    const int slot = id2 >> 3;
    const int b    = ((slot >> 6) << 3) | (id2 & 7);
    const int q0   = (slot & 63) * BQ;

    if (tid < BQ) rowsum[tid] = 0.f;

    {
        const int row  = tid >> 5;
        const int segE = (tid & 31) * 64;
        unsigned long long bits = 0ull;
        if (mstride == 1) {
            const unsigned char* mp = M + (size_t)b * S_LEN * S_LEN
                                        + (size_t)(q0 + row) * S_LEN + segE;
            #pragma unroll
            for (int j = 0; j < 4; ++j)
                bits |= (unsigned long long)nzmask16(*(const u32x4_t*)(mp + j * 16))
                        << (16 * j);
        } else {
            const unsigned* mp = (const unsigned*)M + (size_t)b * S_LEN * S_LEN
                                   + (size_t)(q0 + row) * S_LEN + segE;
            #pragma unroll
            for (int j = 0; j < 16; ++j)
                bits |= (unsigned long long)nzmask4w(*(const u32x4_t*)(mp + j * 4))
                        << (4 * j);
        }
        *(unsigned long long*)&Bm[row * BMSTR + (segE >> 3)] = bits;
    }

    bf16x8_t af[2][2];
    #pragma unroll
    for (int m = 0; m < 2; ++m)
        #pragma unroll
        for (int kk = 0; kk < 2; ++kk) {
            const float* qp = Q + ((size_t)b * S_LEN + q0 + m * 16 + col) * HDIM + kk * 32 + kg * 8;
            const f32x4_t qa = *(const f32x4_t*)qp;
            const f32x4_t qb = *(const f32x4_t*)(qp + 4);
            PK8(qa, qb, af[m][kk]);
        }
    __syncthreads();

    float rs0 = 0.f, rs1 = 0.f;
    {
        const float* Kb = K + (size_t)b * S_LEN * HDIM;
        f32x4_t A0,B0,C0,D0, A1,B1,C1,D1;
#define LDK(f, AX,BX,CX,DX) { \
    const float* kp = Kb + (size_t)((f) * 16 + col) * HDIM + kg * 8; /* HOT: rows 0-127 */ \
    AX = *(const f32x4_t*)kp;        BX = *(const f32x4_t*)(kp + 4); \
    CX = *(const f32x4_t*)(kp + 32); DX = *(const f32x4_t*)(kp + 36); }
#define STEP(f, AX,BX,CX,DX, PF, fp) { \
    bf16x8_t kb0, kb1; PK8(AX, BX, kb0); PK8(CX, DX, kb1); \
    if (PF) LDK(fp, AX,BX,CX,DX); \
    f32x4_t acc0 = {0.f,0.f,0.f,0.f}, acc1 = {0.f,0.f,0.f,0.f}; \
    acc0 = __builtin_amdgcn_mfma_f32_16x16x32_bf16(kb0, af[0][0], acc0, 0,0,0); \
    acc0 = __builtin_amdgcn_mfma_f32_16x16x32_bf16(kb1, af[0][1], acc0, 0,0,0); \
    acc1 = __builtin_amdgcn_mfma_f32_16x16x32_bf16(kb0, af[1][0], acc1, 0,0,0); \
    acc1 = __builtin_amdgcn_mfma_f32_16x16x32_bf16(kb1, af[1][1], acc1, 0,0,0); \
    const int c0 = w * 128 + (f) * 16 + kg * 4; \
    const int sh = c0 & 7; \
    { const unsigned bb = Bm[col * BMSTR + (c0 >> 3)]; \
      float p0 = ((bb >> (sh    )) & 1u) ? 0.f : __expf(acc0[0] * 0.125f); \
      float p1 = ((bb >> (sh + 1)) & 1u) ? 0.f : __expf(acc0[1] * 0.125f); \
      float p2 = ((bb >> (sh + 2)) & 1u) ? 0.f : __expf(acc0[2] * 0.125f); \
      float p3 = ((bb >> (sh + 3)) & 1u) ? 0.f : __expf(acc0[3] * 0.125f); \
      rs0 += (p0 + p1) + (p2 + p3); \
      s16x4_t pk; pk[0]=f2bf(p0); pk[1]=f2bf(p1); pk[2]=f2bf(p2); pk[3]=f2bf(p3); \
      *(s16x4_t*)pelem(Plds, col, c0) = pk; } \
    { const unsigned bb = Bm[(16 + col) * BMSTR + (c0 >> 3)]; \
      float p0 = ((bb >> (sh    )) & 1u) ? 0.f : __expf(acc1[0] * 0.125f); \
      float p1 = ((bb >> (sh + 1)) & 1u) ? 0.f : __expf(acc1[1] * 0.125f); \
      float p2 = ((bb >> (sh + 2)) & 1u) ? 0.f : __expf(acc1[2] * 0.125f); \
      float p3 = ((bb >> (sh + 3)) & 1u) ? 0.f : __expf(acc1[3] * 0.125f); \
      rs1 += (p0 + p1) + (p2 + p3); \
      s16x4_t pk; pk[0]=f2bf(p0); pk[1]=f2bf(p1); pk[2]=f2bf(p2); pk[3]=f2bf(p3); \
      *(s16x4_t*)pelem(Plds, 16 + col, c0) = pk; } }
        LDK(0, A0,B0,C0,D0);
        LDK(1, A1,B1,C1,D1);
        #pragma unroll
        for (int ff = 0; ff < 8; ff += 2) {
            STEP(ff,     A0,B0,C0,D0, (ff + 2 < 8), ff + 2);
            STEP(ff + 1, A1,B1,C1,D1, (ff + 3 < 8), ff + 3);
        }
#undef LDK
#undef STEP
    }
    {
        float s0 = rs0, s1 = rs1;
        s0 += __shfl_xor(s0, 16); s0 += __shfl_xor(s0, 32);
        s1 += __shfl_xor(s1, 16); s1 += __shfl_xor(s1, 32);
        if (lane < 16) {
            atomicAdd(&rowsum[col], s0);
            atomicAdd(&rowsum[16 + col], s1);
        }
    }
    __syncthreads();
    if (tid < BQ) rinv_s[tid] = 1.0f / rowsum[tid];
    __syncthreads();
    // keep P + rinv live; garbage into ctx region (overwritten by main)
    const float g = bf2f(*pelemc(Plds, tid & 31, (tid >> 5) * 64 + col));
    if (lane == 0)
        OUT[((size_t)b * S_LEN + q0 + (w & 31)) * HDIM + 1] = (g + rinv_s[w & 31]) * 1e-30f;
}

// MAIN: r17 verbatim (passes, 451 us).
__global__ __launch_bounds__(NTHREADS, 1)
void sdpa_one(const float* __restrict__ Q, const float* __restrict__ K,
              const float* __restrict__ V, const unsigned char* __restrict__ M,
              const int* __restrict__ MF, float* __restrict__ OUT)
{
    __shared__ short Plds[BQ * (PSTR_B / 2)];
    __shared__ unsigned char Bm[BQ * BMSTR];
    __shared__ float Pvx[BQ][HDIM];
    __shared__ float rowsum[BQ];
    __shared__ float rinv_s[BQ];

    const int tid  = threadIdx.x;
    const int w    = tid >> 6;
    const int lane = tid & 63;
    const int col  = lane & 15;
    const int kg   = lane >> 4;
    const int mstride = MF[0];

    const int id   = blockIdx.x;
    const int slot = id >> 3;
    const int b    = ((slot >> 6) << 3) | (id & 7);
    const int q0   = (slot & 63) * BQ;

    float* attn_out = OUT + (size_t)32 * S_LEN * HDIM;

    if (tid < BQ) rowsum[tid] = 0.f;
    {
        float* pz = &Pvx[0][0];
        pz[tid] = 0.f;
        pz[tid + 1024] = 0.f;
    }

    {
        const int row  = tid >> 5;
        const int segE = (tid & 31) * 64;
        unsigned long long bits = 0ull;
        if (mstride == 1) {
            const unsigned char* mp = M + (size_t)b * S_LEN * S_LEN
                                        + (size_t)(q0 + row) * S_LEN + segE;
            #pragma unroll
            for (int j = 0; j < 4; ++j)
                bits |= (unsigned long long)nzmask16(*(const u32x4_t*)(mp + j * 16))
                        << (16 * j);
        } else {
            const unsigned* mp = (const unsigned*)M + (size_t)b * S_LEN * S_LEN
                                   + (size_t)(q0 + row) * S_LEN + segE;
            #pragma unroll
            for (int j = 0; j < 16; ++j)
                bits |= (unsigned long long)nzmask4w(*(const u32x4_t*)(mp + j * 4))
                        << (4 * j);
        }
        *(unsigned long long*)&Bm[row * BMSTR + (segE >> 3)] = bits;
    }

    bf16x8_t af[2][2];
    #pragma unroll
    for (int m = 0; m < 2; ++m)
        #pragma unroll
        for (int kk = 0; kk < 2; ++kk) {
            const float* qp = Q + ((size_t)b * S_LEN + q0 + m * 16 + col) * HDIM + kk * 32 + kg * 8;
            const f32x4_t qa = *(const f32x4_t*)qp;
            const f32x4_t qb = *(const f32x4_t*)(qp + 4);
            PK8(qa, qb, af[m][kk]);
        }
    __syncthreads();

    float rs0 = 0.f, rs1 = 0.f;
    {
        const float* Kb = K + (size_t)b * S_LEN * HDIM;
        f32x4_t A0,B0,C0,D0, A1,B1,C1,D1;
#define LDK(f, AX,BX,CX,DX) { \
    const float* kp = Kb + (size_t)(w * 128 + (f) * 16 + col) * HDIM + kg * 8; \
    AX = *(const f32x4_t*)kp;        BX = *(const f32x4_t*)(kp + 4); \
    CX = *(const f32x4_t*)(kp + 32); DX = *(const f32x4_t*)(kp + 36); }
#define STEP(f, AX,BX,CX,DX, PF, fp) { \
    bf16x8_t kb0, kb1; PK8(AX, BX, kb0); PK8(CX, DX, kb1); \
    if (PF) LDK(fp, AX,BX,CX,DX); \
    f32x4_t acc0 = {0.f,0.f,0.f,0.f}, acc1 = {0.f,0.f,0.f,0.f}; \
    acc0 = __builtin_amdgcn_mfma_f32_16x16x32_bf16(kb0, af[0][0], acc0, 0,0,0); \
    acc0 = __builtin_amdgcn_mfma_f32_16x16x32_bf16(kb1, af[0][1], acc0, 0,0,0); \
    acc1 = __builtin_amdgcn_mfma_f32_16x16x32_bf16(kb0, af[1][0], acc1, 0,0,0); \
    acc1 = __builtin_amdgcn_mfma_f32_16x16x32_bf16(kb1, af[1][1], acc1, 0,0,0); \
    const int c0 = w * 128 + (f) * 16 + kg * 4; \
    const int sh = c0 & 7; \
    { const unsigned bb = Bm[col * BMSTR + (c0 >> 3)]; \
      float p0 = ((bb >> (sh    )) & 1u) ? 0.f : __expf(acc0[0] * 0.125f); \
      float p1 = ((bb >> (sh + 1)) & 1u) ? 0.f : __expf(acc0[1] * 0.125f); \
      float p2 = ((bb >> (sh + 2)) & 1u) ? 0.f : __expf(acc0[2] * 0.125f); \
      float p3 = ((bb >> (sh + 3)) & 1u) ? 0.f : __expf(acc0[3] * 0.125f); \
      rs0 += (p0 + p1) + (p2 + p3); \
      s16x4_t pk; pk[0]=f2bf(p0); pk[1]=f2bf(p1); pk[2]=f2bf(p2); pk[3]=f2bf(p3); \
      *(s16x4_t*)pelem(Plds, col, c0) = pk; } \
    { const unsigned bb = Bm[(16 + col) * BMSTR + (c0 >> 3)]; \
      float p0 = ((bb >> (sh    )) & 1u) ? 0.f : __expf(acc1[0] * 0.125f); \
      float p1 = ((bb >> (sh + 1)) & 1u) ? 0.f : __expf(acc1[1] * 0.125f); \
      float p2 = ((bb >> (sh + 2)) & 1u) ? 0.f : __expf(acc1[2] * 0.125f); \
      float p3 = ((bb >> (sh + 3)) & 1u) ? 0.f : __expf(acc1[3] * 0.125f); \
      rs1 += (p0 + p1) + (p2 + p3); \
      s16x4_t pk; pk[0]=f2bf(p0); pk[1]=f2bf(p1); pk[2]=f2bf(p2); pk[3]=f2bf(p3); \
      *(s16x4_t*)pelem(Plds, 16 + col, c0) = pk; } }
        LDK(0, A0,B0,C0,D0);
        LDK(1, A1,B1,C1,D1);
        #pragma unroll
        for (int ff = 0; ff < 8; ff += 2) {
            STEP(ff,     A0,B0,C0,D0, (ff + 2 < 8), ff + 2);
            STEP(ff + 1, A1,B1,C1,D1, (ff + 3 < 8), ff + 3);
        }
#undef LDK
#undef STEP
    }
    {
        float s0 = rs0, s1 = rs1;
        s0 += __shfl_xor(s0, 16); s0 += __shfl_xor(s0, 32);
        s1 += __shfl_xor(s1, 16); s1 += __shfl_xor(s1, 32);
        if (lane < 16) {
            atomicAdd(&rowsum[col], s0);
            atomicAdd(&rowsum[16 + col], s1);
        }
    }
    __syncthreads();
    if (tid < BQ) rinv_s[tid] = 1.0f / rowsum[tid];
    __syncthreads();

    const int hb    = (w & 3) * 16;
    const int kbase = (w >> 2) * 512;
    const float* Vb = V + (size_t)b * S_LEN * HDIM;

    f32x4_t cacc0 = {0.f,0.f,0.f,0.f}, cacc1 = {0.f,0.f,0.f,0.f};
    {
        float vr0[8], vr1[8];
#define LOADV(kc, dst) { \
    const float* vp = Vb + (size_t)(kbase + (kc) * 32 + kg * 8) * HDIM + hb + col; \
    dst[0] = vp[0];        dst[1] = vp[HDIM];     dst[2] = vp[2*HDIM]; dst[3] = vp[3*HDIM]; \
    dst[4] = vp[4*HDIM];   dst[5] = vp[5*HDIM];   dst[6] = vp[6*HDIM]; dst[7] = vp[7*HDIM]; }
#define PVSTEP(kc, vsrc) { \
    bf16x8_t vbf; PKV(vsrc, vbf); \
    const int ke = kbase + (kc) * 32 + kg * 8; \
    const bf16x8_t pa0 = *(const bf16x8_t*)pelemc(Plds, col,      ke); \
    const bf16x8_t pa1 = *(const bf16x8_t*)pelemc(Plds, 16 + col, ke); \
    cacc0 = __builtin_amdgcn_mfma_f32_16x16x32_bf16(pa0, vbf, cacc0, 0,0,0); \
    cacc1 = __builtin_amdgcn_mfma_f32_16x16x32_bf16(pa1, vbf, cacc1, 0,0,0); }
        LOADV(0, vr0); LOADV(1, vr1);
        #pragma unroll
        for (int kc = 0; kc < 14; kc += 2) {
            PVSTEP(kc,     vr0); LOADV(kc + 2, vr0);
            PVSTEP(kc + 1, vr1); LOADV(kc + 3, vr1);
        }
        PVSTEP(14, vr0);
        PVSTEP(15, vr1);
#undef LOADV
#undef PVSTEP
    }
    #pragma unroll
    for (int r = 0; r < 4; ++r) {
        atomicAdd(&Pvx[kg * 4 + r][hb + col],      cacc0[r]);
        atomicAdd(&Pvx[16 + kg * 4 + r][hb + col], cacc1[r]);
    }

    {
        const int srow = w * 2 + (lane >> 5);
        const int lc   = lane & 31;
        const float my_rinv = rinv_s[srow];
        float* abp = attn_out + ((size_t)b * S_LEN + q0 + srow) * S_LEN + lc * 4;
        #pragma unroll 4
        for (int sec = 0; sec < 16; ++sec) {
            const s16x4_t pv = *(const s16x4_t*)pelemc(Plds, srow, sec * 128 + lc * 4);
            f32x4_t o;
            o[0] = bf2f(pv[0]) * my_rinv; o[1] = bf2f(pv[1]) * my_rinv;
            o[2] = bf2f(pv[2]) * my_rinv; o[3] = bf2f(pv[3]) * my_rinv;
            *(f32x4_t*)(abp + sec * 128) = o;
        }
    }

    __syncthreads();
    {
        const int row = tid >> 5;
        const int c0  = (tid & 31) * 2;
        const float ri = rinv_s[row];
        float2 o;
        o.x = Pvx[row][c0]     * ri;
        o.y = Pvx[row][c0 + 1] * ri;
        *(float2*)(OUT + ((size_t)b * S_LEN + q0 + row) * HDIM + c0) = o;
    }
}

extern "C" void kernel_launch(void* const* d_in, const int* in_sizes, int n_in,
                              void* d_out, int out_size, void* d_ws, size_t ws_size,
                              hipStream_t stream)
{
    const float* q = (const float*)d_in[0];
    const float* k = (const float*)d_in[1];
    const float* v = (const float*)d_in[2];
    const unsigned char* mask = (const unsigned char*)d_in[3];
    int* mflags = (int*)d_ws;
    float* out = (float*)d_out;
    detect_mask<<<dim3(1), dim3(256), 0, stream>>>(mask, mflags);
    // diagnostics (garbage outputs fully overwritten by main below)
    probe_k  <<<dim3(4096), dim3(NTHREADS), 0, stream>>>(q, k, out);
    probe_ser<<<dim3(4096), dim3(NTHREADS), 0, stream>>>(q, k, mask, mflags, out);
    // real kernel (r17 verbatim)
    sdpa_one<<<dim3(2048), dim3(NTHREADS), 0, stream>>>(q, k, v, mask, mflags, out);
}

// Round 19
// 407.139 us; speedup vs baseline: 3.0405x; 3.0405x over previous
//
#include <hip/hip_runtime.h>
#include <hip/hip_bf16.h>

typedef __bf16    bf16x8_t __attribute__((ext_vector_type(8)));
typedef float     f32x4_t  __attribute__((ext_vector_type(4)));
typedef short     s16x4_t  __attribute__((ext_vector_type(4)));
typedef short     s16x8_t  __attribute__((ext_vector_type(8)));
typedef unsigned  u32x4_t  __attribute__((ext_vector_type(4)));

#define S_LEN 2048
#define HDIM  64
#define BQ    32
#define NTHREADS 1024
#define PSTR_B 4112       // P row byte stride; %128B=16 -> rows shift 4 banks
#define BMSTR 272         // 16B-aligned rows (b128 window reads)
#define KV_ELEMS (32 * S_LEN * HDIM)   // 4,194,304 per tensor

__device__ __forceinline__ short f2bf(float f) {
    return __builtin_bit_cast(short, (__bf16)f);
}
__device__ __forceinline__ float bf2f(short s) {
    return __builtin_bit_cast(float, ((unsigned)(unsigned short)s) << 16);
}
__device__ __forceinline__ short* pelem(short* P, int row, int e) {
    return (short*)((char*)P + (unsigned)row * PSTR_B + (unsigned)e * 2u);
}
__device__ __forceinline__ const short* pelemc(const short* P, int row, int e) {
    return pelem(const_cast<short*>(P), row, e);
}
__device__ __forceinline__ unsigned nzmask16(u32x4_t w) {
    unsigned n = 0;
    #pragma unroll
    for (int i = 0; i < 4; ++i) {
        const unsigned x = w[i];
        const unsigned t = (x & 0x7F7F7F7Fu) + 0x7F7F7F7Fu;
        const unsigned z = ((t | x) & 0x80808080u) >> 7;
        n |= ((z * 0x10204081u) >> 28) << (4 * i);
    }
    return n;
}
__device__ __forceinline__ unsigned nzmask4w(u32x4_t w) {
    return (w[0] ? 1u : 0u) | (w[1] ? 2u : 0u) | (w[2] ? 4u : 0u) | (w[3] ? 8u : 0u);
}

__global__ void detect_mask(const unsigned char* __restrict__ M, int* __restrict__ flags) {
    __shared__ int cnt[4];
    if (threadIdx.x < 4) cnt[threadIdx.x] = 0;
    __syncthreads();
    int local[4] = {0, 0, 0, 0};
    for (int i = threadIdx.x; i < 16384; i += 256)
        if (M[i]) local[i & 3]++;
    #pragma unroll
    for (int c = 0; c < 4; ++c)
        if (local[c]) atomicAdd(&cnt[c], local[c]);
    __syncthreads();
    if (threadIdx.x == 0) {
        int stride;
        if (cnt[1] == 0 && cnt[2] == 0 && cnt[3] == 0)      stride = 4;  // int32
        else if (cnt[0] == 0 && cnt[1] == 0)                stride = 4;  // float32
        else                                                stride = 1;  // bool/int8
        flags[0] = stride;
    }
}

// Prepass: K,V fp32 -> bf16 (RNE, same rounding the main kernel used per-load).
// Halves K/V bytes through L2 and removes all pack-cvt VALU from hot loops.
__global__ __launch_bounds__(256)
void to_bf16(const float* __restrict__ K, const float* __restrict__ V,
             short* __restrict__ Kb, short* __restrict__ Vb)
{
    const size_t i = ((size_t)blockIdx.x * 256 + threadIdx.x) * 4;  // grid covers exactly KV_ELEMS
    const f32x4_t k4 = *(const f32x4_t*)(K + i);
    const f32x4_t v4 = *(const f32x4_t*)(V + i);
    s16x4_t ks, vs;
    ks[0] = f2bf(k4[0]); ks[1] = f2bf(k4[1]); ks[2] = f2bf(k4[2]); ks[3] = f2bf(k4[3]);
    vs[0] = f2bf(v4[0]); vs[1] = f2bf(v4[1]); vs[2] = f2bf(v4[2]); vs[3] = f2bf(v4[3]);
    *(s16x4_t*)(Kb + i) = ks;
    *(s16x4_t*)(Vb + i) = vs;
}

// r17 structure + (a) K/V consumed as pre-converted bf16 (half bytes, no
// PK8/PKV), (b) per-lane mask bits held in REGISTERS (2x b128 window loads,
// compile-time word/shift extraction) -> zero per-STEP Bm LDS reads.
__global__ __launch_bounds__(NTHREADS, 1)
void sdpa_one(const float* __restrict__ Q, const short* __restrict__ Kbf,
              const short* __restrict__ Vbf, const unsigned char* __restrict__ M,
              const int* __restrict__ MF, float* __restrict__ OUT)
{
    __shared__ short Plds[BQ * (PSTR_B / 2)];      // 131584 B unnormalized exp bf16
    __shared__ unsigned char Bm[BQ * BMSTR];       // 8704 B mask bits
    __shared__ float Pvx[BQ][HDIM];                // 8192 B PV accumulator
    __shared__ float rowsum[BQ];
    __shared__ float rinv_s[BQ];

    const int tid  = threadIdx.x;
    const int w    = tid >> 6;        // 0..15
    const int lane = tid & 63;
    const int col  = lane & 15;
    const int kg   = lane >> 4;
    const int mstride = MF[0];

    // 2048 blocks = 8 xcd * 256 slots (bijective)
    const int id   = blockIdx.x;
    const int slot = id >> 3;
    const int b    = ((slot >> 6) << 3) | (id & 7);
    const int q0   = (slot & 63) * BQ;

    float* attn_out = OUT + (size_t)32 * S_LEN * HDIM;

    if (tid < BQ) rowsum[tid] = 0.f;
    {   // zero PV accumulator
        float* pz = &Pvx[0][0];
        pz[tid] = 0.f;
        pz[tid + 1024] = 0.f;
    }

    {   // ---- mask tile -> 1-bit/elem LDS bitmask
        const int row  = tid >> 5;            // 0..31
        const int segE = (tid & 31) * 64;
        unsigned long long bits = 0ull;
        if (mstride == 1) {
            const unsigned char* mp = M + (size_t)b * S_LEN * S_LEN
                                        + (size_t)(q0 + row) * S_LEN + segE;
            #pragma unroll
            for (int j = 0; j < 4; ++j)
                bits |= (unsigned long long)nzmask16(*(const u32x4_t*)(mp + j * 16))
                        << (16 * j);
        } else {
            const unsigned* mp = (const unsigned*)M + (size_t)b * S_LEN * S_LEN
                                   + (size_t)(q0 + row) * S_LEN + segE;
            #pragma unroll
            for (int j = 0; j < 16; ++j)
                bits |= (unsigned long long)nzmask4w(*(const u32x4_t*)(mp + j * 4))
                        << (4 * j);
        }
        *(unsigned long long*)&Bm[row * BMSTR + (segE >> 3)] = bits;
    }

    // Q fragments (fp32 -> bf16 once; MFMA B-operand after swap)
    bf16x8_t af[2][2];
    #pragma unroll
    for (int m = 0; m < 2; ++m)
        #pragma unroll
        for (int kk = 0; kk < 2; ++kk) {
            const float* qp = Q + ((size_t)b * S_LEN + q0 + m * 16 + col) * HDIM + kk * 32 + kg * 8;
            const f32x4_t qa = *(const f32x4_t*)qp;
            const f32x4_t qb = *(const f32x4_t*)(qp + 4);
            s16x8_t t;
            t[0]=f2bf(qa[0]); t[1]=f2bf(qa[1]); t[2]=f2bf(qa[2]); t[3]=f2bf(qa[3]);
            t[4]=f2bf(qb[0]); t[5]=f2bf(qb[1]); t[6]=f2bf(qb[2]); t[7]=f2bf(qb[3]);
            af[m][kk] = __builtin_bit_cast(bf16x8_t, t);
        }
    __syncthreads();

    // per-lane mask windows for THIS wave's 128 k-cols, held in registers.
    // bitpos within window = 16f + 4kg + r -> word f>>1, shift (f&1)*16+4kg+r.
    const u32x4_t mw0 = *(const u32x4_t*)&Bm[col * BMSTR + w * 16];
    const u32x4_t mw1 = *(const u32x4_t*)&Bm[(16 + col) * BMSTR + w * 16];

    // ---- Phase 1: swapped QK^T from bf16 K. D = mfma(K_frag, Q_frag):
    // lane(col,kg) reg r -> P[m*16+col][w*128 + f*16 + kg*4 + r].
    float rs0 = 0.f, rs1 = 0.f;
    {
        const short* Kb = Kbf + (size_t)b * S_LEN * HDIM;
#define STEP(f) { \
    const short* kp_ = Kb + (size_t)(w * 128 + (f) * 16 + col) * HDIM + kg * 8; \
    const bf16x8_t kb0 = *(const bf16x8_t*)kp_; \
    const bf16x8_t kb1 = *(const bf16x8_t*)(kp_ + 32); \
    f32x4_t acc0 = {0.f,0.f,0.f,0.f}, acc1 = {0.f,0.f,0.f,0.f}; \
    acc0 = __builtin_amdgcn_mfma_f32_16x16x32_bf16(kb0, af[0][0], acc0, 0,0,0); \
    acc0 = __builtin_amdgcn_mfma_f32_16x16x32_bf16(kb1, af[0][1], acc0, 0,0,0); \
    acc1 = __builtin_amdgcn_mfma_f32_16x16x32_bf16(kb0, af[1][0], acc1, 0,0,0); \
    acc1 = __builtin_amdgcn_mfma_f32_16x16x32_bf16(kb1, af[1][1], acc1, 0,0,0); \
    const int c0 = w * 128 + (f) * 16 + kg * 4; \
    const unsigned bb0 = mw0[(f) >> 1] >> (((f) & 1) * 16 + kg * 4); \
    const unsigned bb1 = mw1[(f) >> 1] >> (((f) & 1) * 16 + kg * 4); \
    { float p0 = (bb0      & 1u) ? 0.f : __expf(acc0[0] * 0.125f); \
      float p1 = ((bb0>>1) & 1u) ? 0.f : __expf(acc0[1] * 0.125f); \
      float p2 = ((bb0>>2) & 1u) ? 0.f : __expf(acc0[2] * 0.125f); \
      float p3 = ((bb0>>3) & 1u) ? 0.f : __expf(acc0[3] * 0.125f); \
      rs0 += (p0 + p1) + (p2 + p3); \
      s16x4_t pk; pk[0]=f2bf(p0); pk[1]=f2bf(p1); pk[2]=f2bf(p2); pk[3]=f2bf(p3); \
      *(s16x4_t*)pelem(Plds, col, c0) = pk; } \
    { float p0 = (bb1      & 1u) ? 0.f : __expf(acc1[0] * 0.125f); \
      float p1 = ((bb1>>1) & 1u) ? 0.f : __expf(acc1[1] * 0.125f); \
      float p2 = ((bb1>>2) & 1u) ? 0.f : __expf(acc1[2] * 0.125f); \
      float p3 = ((bb1>>3) & 1u) ? 0.f : __expf(acc1[3] * 0.125f); \
      rs1 += (p0 + p1) + (p2 + p3); \
      s16x4_t pk; pk[0]=f2bf(p0); pk[1]=f2bf(p1); pk[2]=f2bf(p2); pk[3]=f2bf(p3); \
      *(s16x4_t*)pelem(Plds, 16 + col, c0) = pk; } }
        STEP(0) STEP(1) STEP(2) STEP(3) STEP(4) STEP(5) STEP(6) STEP(7)
#undef STEP
    }
    {
        float s0 = rs0, s1 = rs1;
        s0 += __shfl_xor(s0, 16); s0 += __shfl_xor(s0, 32);
        s1 += __shfl_xor(s1, 16); s1 += __shfl_xor(s1, 32);
        if (lane < 16) {
            atomicAdd(&rowsum[col], s0);
            atomicAdd(&rowsum[16 + col], s1);
        }
    }
    __syncthreads();
    if (tid < BQ) rinv_s[tid] = 1.0f / rowsum[tid];
    __syncthreads();

    // ---- Phase 2a: pure PV from bf16 V, k in QUARTERS across 16 waves.
    const int hb    = (w & 3) * 16;
    const int kbase = (w >> 2) * 512;
    const short* Vb = Vbf + (size_t)b * S_LEN * HDIM;

    f32x4_t cacc0 = {0.f,0.f,0.f,0.f}, cacc1 = {0.f,0.f,0.f,0.f};
    {
        s16x8_t vr0, vr1;
#define LOADV(kc, dst) { \
    const short* vp = Vb + (size_t)(kbase + (kc) * 32 + kg * 8) * HDIM + hb + col; \
    dst[0] = vp[0];        dst[1] = vp[HDIM];     dst[2] = vp[2*HDIM]; dst[3] = vp[3*HDIM]; \
    dst[4] = vp[4*HDIM];   dst[5] = vp[5*HDIM];   dst[6] = vp[6*HDIM]; dst[7] = vp[7*HDIM]; }
#define PVSTEP(kc, vsrc) { \
    const bf16x8_t vbf = __builtin_bit_cast(bf16x8_t, vsrc); \
    const int ke = kbase + (kc) * 32 + kg * 8; \
    const bf16x8_t pa0 = *(const bf16x8_t*)pelemc(Plds, col,      ke); \
    const bf16x8_t pa1 = *(const bf16x8_t*)pelemc(Plds, 16 + col, ke); \
    cacc0 = __builtin_amdgcn_mfma_f32_16x16x32_bf16(pa0, vbf, cacc0, 0,0,0); \
    cacc1 = __builtin_amdgcn_mfma_f32_16x16x32_bf16(pa1, vbf, cacc1, 0,0,0); }
        LOADV(0, vr0); LOADV(1, vr1);
        #pragma unroll
        for (int kc = 0; kc < 14; kc += 2) {
            PVSTEP(kc,     vr0); LOADV(kc + 2, vr0);
            PVSTEP(kc + 1, vr1); LOADV(kc + 3, vr1);
        }
        PVSTEP(14, vr0);
        PVSTEP(15, vr1);
#undef LOADV
#undef PVSTEP
    }
    #pragma unroll
    for (int r = 0; r < 4; ++r) {
        atomicAdd(&Pvx[kg * 4 + r][hb + col],      cacc0[r]);
        atomicAdd(&Pvx[16 + kg * 4 + r][hb + col], cacc1[r]);
    }

    // ---- Phase 2b: attn store stream — 16 waves x 2 rows, 512B/instr
    {
        const int srow = w * 2 + (lane >> 5);
        const int lc   = lane & 31;
        const float my_rinv = rinv_s[srow];
        float* abp = attn_out + ((size_t)b * S_LEN + q0 + srow) * S_LEN + lc * 4;
        #pragma unroll 4
        for (int sec = 0; sec < 16; ++sec) {
            const s16x4_t pv = *(const s16x4_t*)pelemc(Plds, srow, sec * 128 + lc * 4);
            f32x4_t o;
            o[0] = bf2f(pv[0]) * my_rinv; o[1] = bf2f(pv[1]) * my_rinv;
            o[2] = bf2f(pv[2]) * my_rinv; o[3] = bf2f(pv[3]) * my_rinv;
            *(f32x4_t*)(abp + sec * 128) = o;
        }
    }

    // ---- ctx: normalize accumulated PV, flat store
    __syncthreads();
    {
        const int row = tid >> 5;
        const int c0  = (tid & 31) * 2;
        const float ri = rinv_s[row];
        float2 o;
        o.x = Pvx[row][c0]     * ri;
        o.y = Pvx[row][c0 + 1] * ri;
        *(float2*)(OUT + ((size_t)b * S_LEN + q0 + row) * HDIM + c0) = o;
    }
}

extern "C" void kernel_launch(void* const* d_in, const int* in_sizes, int n_in,
                              void* d_out, int out_size, void* d_ws, size_t ws_size,
                              hipStream_t stream)
{
    const float* q = (const float*)d_in[0];
    const float* k = (const float*)d_in[1];
    const float* v = (const float*)d_in[2];
    const unsigned char* mask = (const unsigned char*)d_in[3];
    float* out = (float*)d_out;

    int*   mflags = (int*)d_ws;
    short* kbf = (short*)((char*)d_ws + (1 << 20));          // +1 MB
    short* vbf = kbf + KV_ELEMS;                             // +8 MB further (17 MB total)

    detect_mask<<<dim3(1), dim3(256), 0, stream>>>(mask, mflags);
    to_bf16<<<dim3(KV_ELEMS / 4 / 256), dim3(256), 0, stream>>>(k, v, kbf, vbf);
    sdpa_one<<<dim3(2048), dim3(NTHREADS), 0, stream>>>(q, kbf, vbf, mask, mflags, out);
}